// Round 8
// baseline (442.919 us; speedup 1.0000x reference)
//
#include <hip/hip_runtime.h>
#include <hip/hip_bf16.h>
#include <math.h>

typedef __attribute__((ext_vector_type(8))) __bf16 bf16x8;
typedef __attribute__((ext_vector_type(4))) float f32x4;

#define IN_DIM 2048
#define NH1 128
#define NH2 64
#define KDIM 1024

__device__ inline f32x4 mfma16(bf16x8 a, bf16x8 b, f32x4 c) {
    return __builtin_amdgcn_mfma_f32_16x16x32_bf16(a, b, c, 0, 0, 0);
}

// ---------------------------------------------------------------------------
// prep: permute W1/W2 into MFMA-fragment order (bf16), pack basis rows with
// c_j = head_w[j] * exp(-||b_j||^2).
// Fragment convention (A and B identical): within a 32-k x 16-col tile,
// lane l, elem e  ->  k = (l>>4)*8 + e , col/row = l&15.
// ---------------------------------------------------------------------------
__global__ void prep_kernel(const float* __restrict__ W1,
                            const float* __restrict__ W2,
                            const float* __restrict__ basis,
                            const float* __restrict__ head_w,
                            __bf16* __restrict__ w1f,
                            __bf16* __restrict__ w2f,
                            float* __restrict__ bp) {
    int idx = blockIdx.x * 256 + threadIdx.x;   // 0 .. 262143
    if (idx < IN_DIM * NH1) {
        int ks = idx >> 12;
        int rem = idx & 4095;
        int c = rem >> 9;
        int q = rem & 511;
        int l = q >> 3, e = q & 7;
        int k = ks * 32 + ((l >> 4) << 3) + e;
        int col = (c << 4) + (l & 15);
        w1f[idx] = (__bf16)W1[k * NH1 + col];
    }
    if (idx < NH1 * NH2) {
        int cb = idx >> 9;
        int c2 = cb >> 2, kb = cb & 3;
        int q = idx & 511;
        int l = q >> 3, e = q & 7;
        int k = kb * 32 + ((l >> 4) << 3) + e;
        int col = (c2 << 4) + (l & 15);
        w2f[idx] = (__bf16)W2[k * NH2 + col];
    }
    if (idx < KDIM) {
        const float* b = basis + idx * 5;
        float n2 = b[0]*b[0] + b[1]*b[1] + b[2]*b[2] + b[3]*b[3] + b[4]*b[4];
        float* o = bp + idx * 8;
        o[0] = b[0]; o[1] = b[1]; o[2] = b[2]; o[3] = b[3]; o[4] = b[4];
        o[5] = 1.0f;
        o[6] = head_w[idx] * expf(-n2);   // gamma = 1
        o[7] = 0.0f;
    }
}

// ---------------------------------------------------------------------------
// fused main: producer/consumer wave split, sequential x streams.
//   Block = 8 waves (4 producers, 4 consumers), 128 consecutive rows, 8
//   phases of 16 rows x full K. Producers: sequential row reads (f32, 8 KB
//   runs) -> regs -> cvt -> XOR-swizzled bf16 LDS panel (2-deep 64 KB ring).
//   Consumers: GEMM1 (A from LDS, B=w1f frags from L2), then per-phase
//   epilogue: h1 tile -> GEMM2 -> GEMM3/conv -> z5s -> RBF -> out.
//   vmcnt streams are pure per wave (producers: x only; consumers: B only).
//   Raw s_barriers (3/phase) + explicit lgkmcnt(0) handoffs; producer loads
//   for phase t+2 stay in flight across all barriers.
// LDS: buf0 @0 (64K), buf1 @65536 (64K), h1 @131072 (4K), z5s @135168 (512),
//      psum @135680 (256) -> 135936 B -> 1 block/CU.
// ---------------------------------------------------------------------------
__launch_bounds__(512, 2)
__global__ void fused_main(const float* __restrict__ x,
                           const __bf16* __restrict__ w1f,
                           const float* __restrict__ b1,
                           const __bf16* __restrict__ w2f,
                           const float* __restrict__ b2,
                           const float* __restrict__ W3,
                           const float* __restrict__ b3,
                           const float* __restrict__ conv_k,
                           const float* __restrict__ conv_b,
                           const float* __restrict__ bp,
                           const float* __restrict__ head_b,
                           float* __restrict__ out) {
    __shared__ __align__(16) char smem[135936];

    const int tid = threadIdx.x;
    const int w = tid >> 6;
    const int l = tid & 63;
    const int r = l & 15;
    const int j = l >> 4;
    const int row0 = blockIdx.x * 128;

    if (w < 4) {
        // ================= PRODUCER ====================================
        const int p = w;
        f32x4 rA[4][8];

        // lane l covers f32 elems [512v + 8l, +8) of its row per pair v
#define P_ISSUE(TT)                                                           \
        {                                                                     \
            _Pragma("unroll")                                                 \
            for (int rr = 0; rr < 4; ++rr) {                                  \
                const float* rp = x + (size_t)(row0 + (TT) * 16 + p * 4 + rr) \
                                    * IN_DIM + 8 * l;                         \
                _Pragma("unroll")                                             \
                for (int v = 0; v < 4; ++v) {                                 \
                    rA[rr][2*v]   = *(const f32x4*)(rp + 512 * v);            \
                    rA[rr][2*v+1] = *(const f32x4*)(rp + 512 * v + 4);        \
                }                                                             \
            }                                                                 \
        }
        // cvt + swizzled write: chunk c = 64v + l  ->  slot c ^ (lrow&7)
#define P_WRITE(BUFW)                                                         \
        {                                                                     \
            _Pragma("unroll")                                                 \
            for (int rr = 0; rr < 4; ++rr) {                                  \
                int lrow = p * 4 + rr;                                        \
                _Pragma("unroll")                                             \
                for (int v = 0; v < 4; ++v) {                                 \
                    f32x4 a = rA[rr][2*v], b = rA[rr][2*v+1];                 \
                    bf16x8 o;                                                 \
                    o[0]=(__bf16)a.x; o[1]=(__bf16)a.y;                       \
                    o[2]=(__bf16)a.z; o[3]=(__bf16)a.w;                       \
                    o[4]=(__bf16)b.x; o[5]=(__bf16)b.y;                       \
                    o[6]=(__bf16)b.z; o[7]=(__bf16)b.w;                       \
                    int c = 64 * v + l;                                       \
                    *(bf16x8*)((BUFW) + lrow * 4096 +                         \
                               ((c ^ (lrow & 7)) << 4)) = o;                  \
                }                                                             \
            }                                                                 \
        }

        // prologue: panel 0 -> buf0; issue panel 1
        P_ISSUE(0)
        P_WRITE(smem)
        asm volatile("s_waitcnt lgkmcnt(0)" ::: "memory");
        __builtin_amdgcn_sched_barrier(0);
        P_ISSUE(1)
        __builtin_amdgcn_s_barrier();

#pragma unroll 1
        for (int t = 0; t < 8; ++t) {
            if (t < 7) {
                char* bufW = smem + (((t + 1) & 1) << 16);
                P_WRITE(bufW)
                asm volatile("s_waitcnt lgkmcnt(0)" ::: "memory");
                __builtin_amdgcn_sched_barrier(0);
                if (t < 6) { P_ISSUE(t + 2) }
            }
            __builtin_amdgcn_s_barrier();   // (1) panel t+1 / h1 ready
            __builtin_amdgcn_s_barrier();   // (2) z5s ready
            __builtin_amdgcn_s_barrier();   // (3) psum ready
        }
    } else {
        // ================= CONSUMER ====================================
        const int cw = w - 4;
        __bf16* h1 = (__bf16*)(smem + 131072);
        float (*z5s)[8] = (float(*)[8])(smem + 135168);
        float* psumB = (float*)(smem + 135680);

        // constants (hoisted out of the phase loop)
        const float b1v0 = b1[(2 * cw) * 16 + r];
        const float b1v1 = b1[(2 * cw + 1) * 16 + r];
        float b2v[4];
#pragma unroll
        for (int c2 = 0; c2 < 4; ++c2) b2v[c2] = b2[c2 * 16 + r];
        float w3l[4][4];
#pragma unroll
        for (int c2 = 0; c2 < 4; ++c2) {
            f32x4 t4 = *(const f32x4*)&W3[(c2 * 16 + r) * 4];
            w3l[c2][0] = t4.x; w3l[c2][1] = t4.y;
            w3l[c2][2] = t4.z; w3l[c2][3] = t4.w;
        }
        const float ck0 = conv_k[0], ck1 = conv_k[1];
        const float ck2 = conv_k[2], ck3 = conv_k[3];
        const float cbv = conv_b[0];
        const float b30 = b3[0], b31 = b3[1], b32 = b3[2], b33 = b3[3];
        const float hbv = head_b[0];
        const float L2E = 1.44269504088896340736f;
        const __bf16* wB0 = w1f + ((2 * cw) << 9) + l * 8;
        const __bf16* wB1 = w1f + ((2 * cw + 1) << 9) + l * 8;

        __builtin_amdgcn_s_barrier();       // prologue: buf0 ready

#pragma unroll 1
        for (int t = 0; t < 8; ++t) {
            const char* bufR = smem + ((t & 1) << 16);
            const char* ar = bufR + r * 4096;

            // ---- GEMM1: 16 rows x 32 cols (this wave), K=2048 ----------
            f32x4 acc0 = (f32x4){0.f, 0.f, 0.f, 0.f};
            f32x4 acc1 = (f32x4){0.f, 0.f, 0.f, 0.f};
#pragma unroll 4
            for (int ks = 0; ks < 64; ++ks) {
                bf16x8 A = *(const bf16x8*)(ar + (((4 * ks + j) ^ (r & 7)) << 4));
                bf16x8 B0 = *(const bf16x8*)(wB0 + ((size_t)ks << 12));
                bf16x8 B1 = *(const bf16x8*)(wB1 + ((size_t)ks << 12));
                acc0 = mfma16(A, B0, acc0);
                acc1 = mfma16(A, B1, acc1);
            }
            // h1 tile write (+b1, relu, bf16)
#pragma unroll
            for (int rr = 0; rr < 4; ++rr) {
                h1[(j * 4 + rr) * NH1 + (2 * cw) * 16 + r] =
                    (__bf16)fmaxf(acc0[rr] + b1v0, 0.f);
                h1[(j * 4 + rr) * NH1 + (2 * cw + 1) * 16 + r] =
                    (__bf16)fmaxf(acc1[rr] + b1v1, 0.f);
            }
            asm volatile("s_waitcnt lgkmcnt(0)" ::: "memory");
            __builtin_amdgcn_sched_barrier(0);
            __builtin_amdgcn_s_barrier();   // (1)

            // ---- GEMM2 (redundant per consumer wave) -------------------
            f32x4 acc2[4];
#pragma unroll
            for (int c2 = 0; c2 < 4; ++c2)
                acc2[c2] = (f32x4){0.f, 0.f, 0.f, 0.f};
#pragma unroll
            for (int kb = 0; kb < 4; ++kb) {
                bf16x8 A = *(const bf16x8*)&h1[r * NH1 + kb * 32 + j * 8];
#pragma unroll
                for (int c2 = 0; c2 < 4; ++c2) {
                    bf16x8 B = *(const bf16x8*)(w2f + (((c2 << 2) + kb) << 9) + l * 8);
                    acc2[c2] = mfma16(A, B, acc2[c2]);
                }
            }
            // ---- GEMM3 + conv/sigmoid -> z5s ---------------------------
            float h2v[4][4];
#pragma unroll
            for (int c2 = 0; c2 < 4; ++c2)
#pragma unroll
                for (int rr = 0; rr < 4; ++rr)
                    h2v[c2][rr] = fmaxf(acc2[c2][rr] + b2v[c2], 0.f);
            float pz[4][4];
#pragma unroll
            for (int rr = 0; rr < 4; ++rr)
#pragma unroll
                for (int jj = 0; jj < 4; ++jj) {
                    float s = 0.f;
#pragma unroll
                    for (int c2 = 0; c2 < 4; ++c2)
                        s = fmaf(h2v[c2][rr], w3l[c2][jj], s);
                    pz[rr][jj] = s;
                }
#pragma unroll
            for (int off = 1; off < 16; off <<= 1)
#pragma unroll
                for (int rr = 0; rr < 4; ++rr)
#pragma unroll
                    for (int jj = 0; jj < 4; ++jj)
                        pz[rr][jj] += __shfl_xor(pz[rr][jj], off, 64);

            if (cw == 0 && r == 0) {
#pragma unroll
                for (int rr = 0; rr < 4; ++rr) {
                    int rl = (j << 2) + rr;
                    float z0 = pz[rr][0] + b30;
                    float z1 = pz[rr][1] + b31;
                    float z2 = pz[rr][2] + b32;
                    float z3 = pz[rr][3] + b33;
                    float s = fmaf(z0, ck0, fmaf(z1, ck1,
                              fmaf(z2, ck2, fmaf(z3, ck3, cbv))));
                    float sg = 1.f / (1.f + expf(-s));
                    float n2 = z0*z0 + z1*z1 + z2*z2 + z3*z3 + sg*sg;
                    z5s[rl][0] = 2.f * L2E * z0;
                    z5s[rl][1] = 2.f * L2E * z1;
                    z5s[rl][2] = 2.f * L2E * z2;
                    z5s[rl][3] = 2.f * L2E * z3;
                    z5s[rl][4] = 2.f * L2E * sg;
                    z5s[rl][5] = -L2E * n2;
                }
            }
            asm volatile("s_waitcnt lgkmcnt(0)" ::: "memory");
            __builtin_amdgcn_sched_barrier(0);
            __builtin_amdgcn_s_barrier();   // (2)

            // ---- RBF: row = r, basis chunk = cw*256 + j*64 -------------
            f32x4 za = *(const f32x4*)&z5s[r][0];
            float z4s = z5s[r][4];
            float z5c = z5s[r][5];
            const float* bpp = bp + (size_t)(cw * 256 + j * 64) * 8;
            float accum = 0.f;
#pragma unroll 4
            for (int i = 0; i < 64; ++i) {
                f32x4 q0 = *(const f32x4*)&bpp[i * 8];
                f32x4 q1 = *(const f32x4*)&bpp[i * 8 + 4];
                float arg = fmaf(za.x, q0.x,
                            fmaf(za.y, q0.y,
                            fmaf(za.z, q0.z,
                            fmaf(za.w, q0.w,
                            fmaf(z4s, q1.x, z5c)))));
                accum = fmaf(q1.z, exp2f(arg), accum);
            }
            accum += __shfl_xor(accum, 16, 64);
            accum += __shfl_xor(accum, 32, 64);
            if (l < 16) psumB[cw * 16 + l] = accum;
            asm volatile("s_waitcnt lgkmcnt(0)" ::: "memory");
            __builtin_amdgcn_sched_barrier(0);
            __builtin_amdgcn_s_barrier();   // (3)

            if (cw == 0 && l < 16)
                out[row0 + t * 16 + l] = psumB[l] + psumB[16 + l]
                                       + psumB[32 + l] + psumB[48 + l] + hbv;
        }
    }
}

// ---------------------------------------------------------------------------
extern "C" void kernel_launch(void* const* d_in, const int* in_sizes, int n_in,
                              void* d_out, int out_size, void* d_ws, size_t ws_size,
                              hipStream_t stream) {
    const float* x     = (const float*)d_in[0];
    const float* W1    = (const float*)d_in[1];
    const float* b1    = (const float*)d_in[2];
    const float* W2    = (const float*)d_in[3];
    const float* b2    = (const float*)d_in[4];
    const float* W3    = (const float*)d_in[5];
    const float* b3    = (const float*)d_in[6];
    const float* ck    = (const float*)d_in[7];
    const float* cb    = (const float*)d_in[8];
    const float* basis = (const float*)d_in[9];
    const float* hwv   = (const float*)d_in[10];
    const float* hb    = (const float*)d_in[11];

    __bf16* w1f = (__bf16*)d_ws;                                 // 524288 B
    __bf16* w2f = (__bf16*)((char*)d_ws + 524288);               // 16384 B
    float*  bpp = (float*)((char*)d_ws + 524288 + 16384);        // 32768 B

    prep_kernel<<<1024, 256, 0, stream>>>(W1, W2, basis, hwv, w1f, w2f, bpp);
    fused_main<<<512, 512, 0, stream>>>(x, w1f, b1, w2f, b2, W3, b3, ck, cb,
                                        bpp, hb, (float*)d_out);
}

// Round 9
// 185.206 us; speedup vs baseline: 2.3915x; 2.3915x over previous
//
#include <hip/hip_runtime.h>
#include <hip/hip_bf16.h>
#include <math.h>

typedef __attribute__((ext_vector_type(8))) __bf16 bf16x8;
typedef __attribute__((ext_vector_type(4))) float f32x4;

#define IN_DIM 2048
#define NH1 128
#define NH2 64
#define KDIM 1024

__device__ inline f32x4 mfma16(bf16x8 a, bf16x8 b, f32x4 c) {
    return __builtin_amdgcn_mfma_f32_16x16x32_bf16(a, b, c, 0, 0, 0);
}

__device__ inline void gld16(const void* g, void* l) {
    __builtin_amdgcn_global_load_lds(
        (const __attribute__((address_space(1))) void*)g,
        (__attribute__((address_space(3))) void*)l, 16, 0, 0);
}

// ---------------------------------------------------------------------------
// prep: permute W1/W2 into MFMA-fragment order (bf16), pack basis rows with
// c_j = head_w[j] * exp(-||b_j||^2).
// Fragment convention (A and B identical): within a 32-k x 16-col tile,
// lane l, elem e  ->  k = (l>>4)*8 + e , col/row = l&15.
// ---------------------------------------------------------------------------
__global__ void prep_kernel(const float* __restrict__ W1,
                            const float* __restrict__ W2,
                            const float* __restrict__ basis,
                            const float* __restrict__ head_w,
                            __bf16* __restrict__ w1f,
                            __bf16* __restrict__ w2f,
                            float* __restrict__ bp) {
    int idx = blockIdx.x * 256 + threadIdx.x;   // 0 .. 262143
    if (idx < IN_DIM * NH1) {
        int ks = idx >> 12;
        int rem = idx & 4095;
        int c = rem >> 9;
        int q = rem & 511;
        int l = q >> 3, e = q & 7;
        int k = ks * 32 + ((l >> 4) << 3) + e;
        int col = (c << 4) + (l & 15);
        w1f[idx] = (__bf16)W1[k * NH1 + col];
    }
    if (idx < NH1 * NH2) {
        int cb = idx >> 9;
        int c2 = cb >> 2, kb = cb & 3;
        int q = idx & 511;
        int l = q >> 3, e = q & 7;
        int k = kb * 32 + ((l >> 4) << 3) + e;
        int col = (c2 << 4) + (l & 15);
        w2f[idx] = (__bf16)W2[k * NH2 + col];
    }
    if (idx < KDIM) {
        const float* b = basis + idx * 5;
        float n2 = b[0]*b[0] + b[1]*b[1] + b[2]*b[2] + b[3]*b[3] + b[4]*b[4];
        float* o = bp + idx * 8;
        o[0] = b[0]; o[1] = b[1]; o[2] = b[2]; o[3] = b[3]; o[4] = b[4];
        o[5] = 1.0f;
        o[6] = head_w[idx] * expf(-n2);   // gamma = 1
        o[7] = 0.0f;
    }
}

// ---------------------------------------------------------------------------
// fused main — granularity test: R6's exact ring/vmcnt/barrier structure,
// stage reshaped {128 rows x 128B} -> {32 rows x 256B} (BM=32, BK=64).
//   block = 4 waves, 32 rows x 128 cols; wave (g = w&1, cb = w>>1) owns the
//   16-row x 64-col quadrant. 32 K-iters of BK=64 (2 ksteps).
//   Stage/iter/wave: 2x A gld16 + 4x B gld16 = 6 -> vmcnt(6), never 0
//   in-loop; 2 raw barriers/iter. 2-deep ring, slot = A 8KB + B 16KB,
//   48 KB total -> 3 blocks/CU (12 waves/CU).
//   A source chunks XOR-pre-swizzled ((l&15) ^ (row&7)) -> linear LDS dest,
//   conflict-free swizzled ds_read_b128 on the fragment reads.
// LDS: slot0 A@0 B@8192; slot1 A@24576 B@32768.
// Overlays: h1 (32x128 bf16, 8KB) @0; z5s @8192; psum @9216.
// ---------------------------------------------------------------------------
__launch_bounds__(256, 3)
__global__ void fused_main(const float* __restrict__ x,
                           const __bf16* __restrict__ w1f,
                           const float* __restrict__ b1,
                           const __bf16* __restrict__ w2f,
                           const float* __restrict__ b2,
                           const float* __restrict__ W3,
                           const float* __restrict__ b3,
                           const float* __restrict__ conv_k,
                           const float* __restrict__ conv_b,
                           const float* __restrict__ bp,
                           const float* __restrict__ head_b,
                           float* __restrict__ out) {
    __shared__ __align__(16) char smem[49152];

    const int tid = threadIdx.x;
    const int w = tid >> 6;
    const int l = tid & 63;
    const int r = l & 15;        // fragment col/row index
    const int j = l >> 4;        // fragment k-group
    const int g = w & 1;         // row-half (16 rows)
    const int cb = w >> 1;       // col-half (64 cols)
    const int row0 = blockIdx.x * 32;

    // ---- staging sources --------------------------------------------------
    // A instr q (2/wave): rows w*8 + q*4 + (l>>4); lane chunk l&15 holds
    // global 16B chunk (l&15) ^ (row&7)  (source pre-swizzle).
    const char* xb = (const char*)x;
    unsigned aByte[2];
#pragma unroll
    for (int q = 0; q < 2; ++q) {
        int rho = w * 8 + q * 4 + (l >> 4);
        aByte[q] = (unsigned)(row0 + rho) * (IN_DIM * 4)
                 + ((unsigned)((l & 15) ^ (rho & 7)) << 4);
    }
    // B: linear 16KB copy per iter (BK=64 = 2 consecutive 8KB kstep tiles)
    const char* w1fb = (const char*)w1f;

#define STAGE_ISSUE(T, AO, BO)                                                \
    {                                                                         \
        _Pragma("unroll")                                                     \
        for (int q = 0; q < 2; ++q)                                           \
            gld16(xb + aByte[q] + (unsigned)(T) * 256u,                       \
                  smem + (AO) + (w * 8 + q * 4) * 256);                       \
        _Pragma("unroll")                                                     \
        for (int q = 0; q < 4; ++q)                                           \
            gld16(w1fb + (unsigned)(T) * 16384u + (w * 4 + q) * 1024 + l * 16,\
                  smem + (BO) + (w * 4 + q) * 1024);                          \
    }

    f32x4 acc[4];
#pragma unroll
    for (int c = 0; c < 4; ++c) acc[c] = (f32x4){0.f, 0.f, 0.f, 0.f};

#define KSTEP(AO, BO)                                                         \
    {                                                                         \
        _Pragma("unroll")                                                     \
        for (int s = 0; s < 2; ++s) {                                         \
            const char* ab = smem + (AO) + (g * 16 + r) * 256;                \
            f32x4 f0 = *(const f32x4*)(ab + (((8*s + 2*j)     ^ (r & 7)) << 4)); \
            f32x4 f1 = *(const f32x4*)(ab + (((8*s + 2*j + 1) ^ (r & 7)) << 4)); \
            bf16x8 Af;                                                        \
            Af[0] = (__bf16)f0.x; Af[1] = (__bf16)f0.y;                       \
            Af[2] = (__bf16)f0.z; Af[3] = (__bf16)f0.w;                       \
            Af[4] = (__bf16)f1.x; Af[5] = (__bf16)f1.y;                       \
            Af[6] = (__bf16)f1.z; Af[7] = (__bf16)f1.w;                       \
            _Pragma("unroll")                                                 \
            for (int c = 0; c < 4; ++c) {                                     \
                bf16x8 Bv = *(const bf16x8*)(smem + (BO)                      \
                              + ((s * 8 + cb * 4 + c) << 10) + l * 16);       \
                acc[c] = mfma16(Af, Bv, acc[c]);                              \
            }                                                                 \
        }                                                                     \
    }

    // ---- prologue: fill the 2-deep ring ----------------------------------
    STAGE_ISSUE(0, 0, 8192)
    STAGE_ISSUE(1, 24576, 32768)
    asm volatile("s_waitcnt vmcnt(6)" ::: "memory");    // stage 0 landed
    __builtin_amdgcn_s_barrier();
    __builtin_amdgcn_sched_barrier(0);

    unsigned aoff = 0;
    // ---- main K-loop: t = 0..29 stage t+2; 30/31 drain -------------------
#pragma unroll 1
    for (int t = 0; t < 30; ++t) {
        KSTEP(aoff, aoff + 8192)
        __builtin_amdgcn_s_barrier();        // all waves done reading slot
        __builtin_amdgcn_sched_barrier(0);
        STAGE_ISSUE(t + 2, aoff, aoff + 8192)   // into just-freed slot
        asm volatile("s_waitcnt vmcnt(6)" ::: "memory");   // stage t+1 landed
        __builtin_amdgcn_s_barrier();
        __builtin_amdgcn_sched_barrier(0);
        aoff ^= 24576u;
    }
    KSTEP(aoff, aoff + 8192)                               // t = 30
    asm volatile("s_waitcnt vmcnt(0)" ::: "memory");       // stage 31 landed
    __builtin_amdgcn_s_barrier();
    __builtin_amdgcn_sched_barrier(0);
    aoff ^= 24576u;
    KSTEP(aoff, aoff + 8192)                               // t = 31

    __builtin_amdgcn_s_barrier();    // slot0 free (last read t=30) -> overlay
    __builtin_amdgcn_sched_barrier(0);

    // ---- epilogue: + b1, relu, bf16 -> block-shared h1 [32][128] ----------
    float b1v[4];
#pragma unroll
    for (int c = 0; c < 4; ++c) b1v[c] = b1[cb * 64 + c * 16 + r];
    __bf16* h1 = (__bf16*)smem;
#pragma unroll
    for (int c = 0; c < 4; ++c)
#pragma unroll
        for (int rr = 0; rr < 4; ++rr)
            h1[(g * 16 + j * 4 + rr) * NH1 + cb * 64 + c * 16 + r] =
                (__bf16)fmaxf(acc[c][rr] + b1v[c], 0.f);

    __syncthreads();

    // ---- stage 2: h2 = relu(h1 @ W2 + b2); wave row-half = g --------------
    f32x4 acc2[4];
#pragma unroll
    for (int c2 = 0; c2 < 4; ++c2) acc2[c2] = (f32x4){0.f, 0.f, 0.f, 0.f};
#pragma unroll
    for (int kb = 0; kb < 4; ++kb) {
        bf16x8 A = *(const bf16x8*)&h1[(g * 16 + r) * NH1 + kb * 32 + j * 8];
#pragma unroll
        for (int c2 = 0; c2 < 4; ++c2) {
            bf16x8 B = *(const bf16x8*)(w2f + (((c2 << 2) + kb) << 9) + l * 8);
            acc2[c2] = mfma16(A, B, acc2[c2]);
        }
    }

    // ---- stage 3: z = h2 @ W3 + b3 ; conv sigmoid -------------------------
    float b2v[4];
#pragma unroll
    for (int c2 = 0; c2 < 4; ++c2) b2v[c2] = b2[c2 * 16 + r];
    float w3l[4][4];
#pragma unroll
    for (int c2 = 0; c2 < 4; ++c2) {
        f32x4 t4 = *(const f32x4*)&W3[(c2 * 16 + r) * 4];
        w3l[c2][0] = t4.x; w3l[c2][1] = t4.y;
        w3l[c2][2] = t4.z; w3l[c2][3] = t4.w;
    }
    float h2v[4][4];
#pragma unroll
    for (int c2 = 0; c2 < 4; ++c2)
#pragma unroll
        for (int rr = 0; rr < 4; ++rr)
            h2v[c2][rr] = fmaxf(acc2[c2][rr] + b2v[c2], 0.f);

    float pz[4][4];
#pragma unroll
    for (int rr = 0; rr < 4; ++rr)
#pragma unroll
        for (int jj = 0; jj < 4; ++jj) {
            float s = 0.f;
#pragma unroll
            for (int c2 = 0; c2 < 4; ++c2) s = fmaf(h2v[c2][rr], w3l[c2][jj], s);
            pz[rr][jj] = s;
        }
#pragma unroll
    for (int off = 1; off < 16; off <<= 1)
#pragma unroll
        for (int rr = 0; rr < 4; ++rr)
#pragma unroll
            for (int jj = 0; jj < 4; ++jj)
                pz[rr][jj] += __shfl_xor(pz[rr][jj], off, 64);

    const float ck0 = conv_k[0], ck1 = conv_k[1], ck2 = conv_k[2], ck3 = conv_k[3];
    const float cbv = conv_b[0];
    const float b30 = b3[0], b31 = b3[1], b32 = b3[2], b33 = b3[3];
    const float L2E = 1.44269504088896340736f;

    float (*z5s)[8] = (float(*)[8])(smem + 8192);
    float* psum = (float*)(smem + 9216);

    if (w < 2 && r == 0) {
#pragma unroll
        for (int rr = 0; rr < 4; ++rr) {
            int rl = g * 16 + (j << 2) + rr;
            float z0 = pz[rr][0] + b30;
            float z1 = pz[rr][1] + b31;
            float z2 = pz[rr][2] + b32;
            float z3 = pz[rr][3] + b33;
            float s = fmaf(z0, ck0, fmaf(z1, ck1, fmaf(z2, ck2, fmaf(z3, ck3, cbv))));
            float sg = 1.f / (1.f + expf(-s));
            float n2 = z0*z0 + z1*z1 + z2*z2 + z3*z3 + sg*sg;
            z5s[rl][0] = 2.f * L2E * z0;
            z5s[rl][1] = 2.f * L2E * z1;
            z5s[rl][2] = 2.f * L2E * z2;
            z5s[rl][3] = 2.f * L2E * z3;
            z5s[rl][4] = 2.f * L2E * sg;
            z5s[rl][5] = -L2E * n2;
        }
    }
    __syncthreads();

    // ---- stage 4: RBF + head (32 rows; 8 groups x 128 basis) --------------
    const int row = tid & 31;
    const int grp = tid >> 5;
    f32x4 za = *(const f32x4*)&z5s[row][0];
    float z4s = z5s[row][4];
    float z5c = z5s[row][5];
    const float* bpp = bp + (size_t)grp * 128 * 8;
    float accum = 0.f;
#pragma unroll 4
    for (int jb = 0; jb < 128; ++jb) {
        f32x4 q0 = *(const f32x4*)&bpp[jb * 8];
        f32x4 q1 = *(const f32x4*)&bpp[jb * 8 + 4];
        float arg = fmaf(za.x, q0.x,
                    fmaf(za.y, q0.y,
                    fmaf(za.z, q0.z,
                    fmaf(za.w, q0.w,
                    fmaf(z4s, q1.x, z5c)))));
        accum = fmaf(q1.z, exp2f(arg), accum);
    }
    psum[grp * 32 + row] = accum;
    __syncthreads();
    if (tid < 32) {
        float s = psum[tid];
#pragma unroll
        for (int q = 1; q < 8; ++q) s += psum[q * 32 + tid];
        out[row0 + tid] = s + head_b[0];
    }
}

// ---------------------------------------------------------------------------
extern "C" void kernel_launch(void* const* d_in, const int* in_sizes, int n_in,
                              void* d_out, int out_size, void* d_ws, size_t ws_size,
                              hipStream_t stream) {
    const float* x     = (const float*)d_in[0];
    const float* W1    = (const float*)d_in[1];
    const float* b1    = (const float*)d_in[2];
    const float* W2    = (const float*)d_in[3];
    const float* b2    = (const float*)d_in[4];
    const float* W3    = (const float*)d_in[5];
    const float* b3    = (const float*)d_in[6];
    const float* ck    = (const float*)d_in[7];
    const float* cb    = (const float*)d_in[8];
    const float* basis = (const float*)d_in[9];
    const float* hwv   = (const float*)d_in[10];
    const float* hb    = (const float*)d_in[11];

    __bf16* w1f = (__bf16*)d_ws;                                 // 524288 B
    __bf16* w2f = (__bf16*)((char*)d_ws + 524288);               // 16384 B
    float*  bpp = (float*)((char*)d_ws + 524288 + 16384);        // 32768 B

    prep_kernel<<<1024, 256, 0, stream>>>(W1, W2, basis, hwv, w1f, w2f, bpp);
    fused_main<<<2048, 256, 0, stream>>>(x, w1f, b1, w2f, b2, W3, b3, ck, cb,
                                         bpp, hb, (float*)d_out);
}